// Round 14
// baseline (77.180 us; speedup 1.0000x reference)
//
#include <hip/hip_runtime.h>
#include <math.h>

#define NPTS 8192
#define DIM 512
#define KNN 5

typedef unsigned short u16;
typedef unsigned int u32;
typedef __attribute__((ext_vector_type(8))) short short8;
typedef __attribute__((ext_vector_type(4))) float f32x4;
typedef __attribute__((ext_vector_type(16))) float f32x16;

// Branch-free sorted insert of v into ascending 5-list.
// Closed form: t_i' = med3(t_{i-1}, t_i, v) (old values), t0' = min(t0, v).
#define INSERT5(t0, t1, t2, t3, t4, v)                \
  do {                                                \
    float _v = (v);                                   \
    float _n4 = __builtin_amdgcn_fmed3f(t3, t4, _v);  \
    float _n3 = __builtin_amdgcn_fmed3f(t2, t3, _v);  \
    float _n2 = __builtin_amdgcn_fmed3f(t1, t2, _v);  \
    float _n1 = __builtin_amdgcn_fmed3f(t0, t1, _v);  \
    t0 = fminf(t0, _v);                               \
    t1 = _n1; t2 = _n2; t3 = _n3; t4 = _n4;           \
  } while (0)

__device__ __forceinline__ u16 f2bf(float f) {
  u32 u = __float_as_uint(f);
  u32 r = (u + 0x7fffu + ((u >> 16) & 1u)) >> 16;  // RNE (no NaN in data)
  return (u16)r;
}

// ---------------------------------------------------------------------------
// Kernel 0: fused bf16 convert (to 64-row-band fragment pack) + row sumsq.
// Band layout: for row r, col k:
//   G = r>>6, mf2 = (r>>5)&1, r32 = r&31; s = k>>5, kk = (k>>4)&1,
//   oct = (k>>3)&1, k8 = k&7
//   addr_u16 = G*32768 + s*2048 + mf2*1024 + kk*512 + (oct*32 + r32)*8 + k8
// => a wave's 8 per-step frag loads are imm offsets {0,512,1024,1536}u16 from
// a per-band pointer advancing 2048 u16 (4KB) per K32 step.
// Fragment-internal mapping: lane&31 = row, lane>>5 = k-octet.
__global__ __launch_bounds__(256) void k_prep(const float* __restrict__ X,
                                              u16* __restrict__ Xp,
                                              float* __restrict__ sq) {
  int gt = blockIdx.x * 256 + threadIdx.x;
  int row = gt >> 6;
  int lane = gt & 63;   // this thread holds k = lane*8 .. lane*8+7 (one octet)
  const float* r = X + (size_t)row * DIM + lane * 8;
  float4 a = *(const float4*)r;
  float4 b = *(const float4*)(r + 4);
  float s = a.x * a.x + a.y * a.y + a.z * a.z + a.w * a.w
          + b.x * b.x + b.y * b.y + b.z * b.z + b.w * b.w;
  u32 o0 = (u32)f2bf(a.x) | ((u32)f2bf(a.y) << 16);
  u32 o1 = (u32)f2bf(a.z) | ((u32)f2bf(a.w) << 16);
  u32 o2 = (u32)f2bf(b.x) | ((u32)f2bf(b.y) << 16);
  u32 o3 = (u32)f2bf(b.z) | ((u32)f2bf(b.w) << 16);
  // k = lane*8: s = lane>>2, kk = (lane>>1)&1, oct = lane&1
  u32 dst = (u32)((row >> 6) * 32768 + (lane >> 2) * 2048 +
                  ((row >> 5) & 1) * 1024 + ((lane >> 1) & 1) * 512 +
                  ((lane & 1) * 32 + (row & 31)) * 8);
  *(uint4*)(Xp + dst) = make_uint4(o0, o1, o2, o3);
#pragma unroll
  for (int o = 32; o > 0; o >>= 1) s += __shfl_down(s, o);
  if (lane == 0) sq[row] = s;
}

// ---------------------------------------------------------------------------
// Kernel 1: symmetric bf16 32x32x16-MFMA distance tiles, triangular grid.
// Flatmm K-loop, SINGLE-buffered frags + rolled loop + __launch_bounds__(256,4)
// -> unified regs (64 AGPR acc + 32 frag + ~25 misc) <= 128 -> 16 waves/CU
// (the 64/128/256 occupancy quantum, m69). Latency hidden by TLP (4 waves/
// SIMD), not ILP. 8x8 super-tile enumeration keeps panels L2-resident.
// C/D: col=lane&31, row=(reg&3)+8*(reg>>2)+4*(lane>>5). part holds SQUARED
// distances (sqrt deferred to k_merge).
__global__ __launch_bounds__(256, 4) void k_knn_sym(
    const u16* __restrict__ Xp, const float* __restrict__ sq,
    float* __restrict__ part) {
  __shared__ __align__(16) char smem[34816];
  float* mbuf = (float*)smem;             // col-epi merge: [wm*2+wn][nf2][32][5]
  float* lsT = (float*)smem;              // row-epi transpose: [128 cols][68]

  const int tid = threadIdx.x;
  const int lane = tid & 63;
  const int wid = tid >> 6;
  const int wm = wid >> 1;
  const int wn = wid & 1;
  const int lh = lane >> 5;               // k-octet / row-half selector

  // XCD-aware bijective remap (2080 = 8 * 260): each XCD gets 260 consecutive
  // t -> ~one 64-tile 8x8 super-tile at a time (2MB panel set, L2-resident).
  int t = (blockIdx.x & 7) * 260 + (blockIdx.x >> 3);
  int bm, bn;
  if (t < 1792) {
    // off-diagonal super-tiles: st = SM*(SM-1)/2 + SN (SM=1..7, SN<SM)
    int st = t >> 6, u = t & 63;
    int SM = (int)((sqrtf(8.f * st + 1.f) + 1.f) * 0.5f);
    while (SM * (SM - 1) / 2 > st) --SM;
    while ((SM + 1) * SM / 2 <= st) ++SM;
    int SN = st - SM * (SM - 1) / 2;
    bm = SM * 8 + (u >> 3);
    bn = SN * 8 + (u & 7);
  } else {
    // diagonal super-tiles: 8 supers x 36 tiles (triangular 8x8 incl. diag)
    int d = t - 1792;
    int SM = d / 36, u = d % 36;
    int im = (int)((sqrtf(8.f * u + 1.f) - 1.f) * 0.5f);
    while ((im + 1) * (im + 2) / 2 <= u) ++im;
    while (im * (im + 1) / 2 > u) --im;
    int in = u - im * (im + 1) / 2;
    bm = SM * 8 + im;
    bn = SM * 8 + in;
  }
  const int n0 = bm * 128;
  const int q0 = bn * 128;

  // Band pointers: band (64 rows) spans 32768 u16; advance 2048 u16 per step.
  const u16* pa = Xp + (size_t)(bm * 2 + wm) * 32768 + lane * 8;
  const u16* pb = Xp + (size_t)(bn * 2 + wn) * 32768 + lane * 8;

  f32x16 acc[2][2];
#pragma unroll
  for (int mf2 = 0; mf2 < 2; ++mf2)
#pragma unroll
    for (int nf2 = 0; nf2 < 2; ++nf2)
#pragma unroll
      for (int r = 0; r < 16; ++r) acc[mf2][nf2][r] = 0.f;

  short8 af[2][2], bf[2][2];
#pragma unroll 1
  for (int step = 0; step < DIM / 32; ++step) {
    af[0][0] = *(const short8*)(pa);
    af[0][1] = *(const short8*)(pa + 512);
    af[1][0] = *(const short8*)(pa + 1024);
    af[1][1] = *(const short8*)(pa + 1536);
    bf[0][0] = *(const short8*)(pb);
    bf[0][1] = *(const short8*)(pb + 512);
    bf[1][0] = *(const short8*)(pb + 1024);
    bf[1][1] = *(const short8*)(pb + 1536);
    pa += 2048;                            // next K32 step (4KB)
    pb += 2048;
    __builtin_amdgcn_s_setprio(1);
#pragma unroll
    for (int kk = 0; kk < 2; ++kk)
#pragma unroll
      for (int mf2 = 0; mf2 < 2; ++mf2)
#pragma unroll
        for (int nf2 = 0; nf2 < 2; ++nf2)
          acc[mf2][nf2] = __builtin_amdgcn_mfma_f32_32x32x16_bf16(
              af[mf2][kk], bf[nf2][kk], acc[mf2][nf2], 0, 0, 0);
    __builtin_amdgcn_s_setprio(0);
  }

  // ---- column epilogue: per query-col top-5 of (sq_row - 2*dot) ----
  int qg[2];
  float sqc[2];
#pragma unroll
  for (int nf2 = 0; nf2 < 2; ++nf2) {
    qg[nf2] = q0 + wn * 64 + nf2 * 32 + (lane & 31);
    sqc[nf2] = sq[qg[nf2]];
  }

  float tl[2][5];
#pragma unroll
  for (int nf2 = 0; nf2 < 2; ++nf2)
#pragma unroll
    for (int j = 0; j < 5; ++j) tl[nf2][j] = 1e30f;

  // diagonal mask needed only on the 64 diagonal tiles (uniform branch)
#define COLSCAN(DIAG)                                                         \
  do {                                                                        \
    _Pragma("unroll")                                                         \
    for (int mf2 = 0; mf2 < 2; ++mf2) {                                       \
      _Pragma("unroll")                                                       \
      for (int q2 = 0; q2 < 4; ++q2) {                                        \
        int ngb = n0 + wm * 64 + mf2 * 32 + q2 * 8 + 4 * lh;                  \
        float4 snv = *(const float4*)&sq[ngb];                                \
        _Pragma("unroll")                                                     \
        for (int j = 0; j < 4; ++j) {                                         \
          float sn = (j == 0) ? snv.x : (j == 1) ? snv.y                      \
                   : (j == 2) ? snv.z : snv.w;                                \
          _Pragma("unroll")                                                   \
          for (int nf2 = 0; nf2 < 2; ++nf2) {                                 \
            float c = fmaf(-2.f, acc[mf2][nf2][q2 * 4 + j], sn);              \
            if (DIAG) c = ((ngb + j) == qg[nf2]) ? -1e30f : c;                \
            INSERT5(tl[nf2][0], tl[nf2][1], tl[nf2][2], tl[nf2][3],           \
                    tl[nf2][4], c);                                           \
          }                                                                   \
        }                                                                     \
      }                                                                       \
    }                                                                         \
  } while (0)

  if (bm == bn) COLSCAN(true); else COLSCAN(false);
#undef COLSCAN

  // merge with partner lane^32 (holds the complementary 32 rows, same col)
#pragma unroll
  for (int nf2 = 0; nf2 < 2; ++nf2) {
    float v0 = __shfl_xor(tl[nf2][0], 32);
    float v1 = __shfl_xor(tl[nf2][1], 32);
    float v2 = __shfl_xor(tl[nf2][2], 32);
    float v3 = __shfl_xor(tl[nf2][3], 32);
    float v4 = __shfl_xor(tl[nf2][4], 32);
    INSERT5(tl[nf2][0], tl[nf2][1], tl[nf2][2], tl[nf2][3], tl[nf2][4], v0);
    INSERT5(tl[nf2][0], tl[nf2][1], tl[nf2][2], tl[nf2][3], tl[nf2][4], v1);
    INSERT5(tl[nf2][0], tl[nf2][1], tl[nf2][2], tl[nf2][3], tl[nf2][4], v2);
    INSERT5(tl[nf2][0], tl[nf2][1], tl[nf2][2], tl[nf2][3], tl[nf2][4], v3);
    INSERT5(tl[nf2][0], tl[nf2][1], tl[nf2][2], tl[nf2][3], tl[nf2][4], v4);
  }

  if (lane < 32) {
#pragma unroll
    for (int nf2 = 0; nf2 < 2; ++nf2)
#pragma unroll
      for (int j = 0; j < 5; ++j)
        mbuf[(((wm * 2 + wn) * 2 + nf2) * 32 + lane) * 5 + j] = tl[nf2][j];
  }
  __syncthreads();

  if (tid < 128) {
    int wn2 = tid >> 6, nf2 = (tid >> 5) & 1, q = tid & 31;
    const float* m0 = &mbuf[(((0 * 2 + wn2) * 2 + nf2) * 32 + q) * 5];
    const float* m1 = &mbuf[(((1 * 2 + wn2) * 2 + nf2) * 32 + q) * 5];
    float b0 = m0[0], b1 = m0[1], b2 = m0[2], b3 = m0[3], b4 = m0[4];
#pragma unroll
    for (int j = 0; j < 5; ++j) {
      float v = m1[j];
      INSERT5(b0, b1, b2, b3, b4, v);
    }
    int qgl = q0 + wn2 * 64 + nf2 * 32 + q;
    float sc = sq[qgl];
    float* o = part + ((size_t)qgl * (NPTS / 128) + bm) * KNN;
    o[0] = b0 + sc;   // squared distances; sqrt deferred to k_merge
    o[1] = b1 + sc;
    o[2] = b2 + sc;
    o[3] = b3 + sc;
    o[4] = b4 + sc;
  }

  // ---- row epilogue (off-diagonal blocks): queries = this tile's rows ----
  // pass p = mf2: rows {wm*64 + p*32 + w32} through lsT[128 cols][68 rows].
  if (bm != bn) {
#pragma unroll
    for (int p = 0; p < 2; ++p) {
      __syncthreads();                     // protect mbuf / previous lsT readers
#pragma unroll
      for (int nf2 = 0; nf2 < 2; ++nf2) {
        int cl = wn * 64 + nf2 * 32 + (lane & 31);
#pragma unroll
        for (int q2 = 0; q2 < 4; ++q2) {
          int rl = wm * 32 + q2 * 8 + 4 * lh;
          f32x4 cp;
#pragma unroll
          for (int j = 0; j < 4; ++j)
            cp[j] = fmaf(-2.f, acc[p][nf2][q2 * 4 + j], sqc[nf2]);
          *(f32x4*)&lsT[cl * 68 + rl] = cp;   // 16B-aligned (rl%4==0)
        }
      }
      __syncthreads();
      int r = tid >> 2, qq = tid & 3;        // 4 threads per row, 32 cols each
      float b0 = 1e30f, b1 = 1e30f, b2 = 1e30f, b3 = 1e30f, b4 = 1e30f;
#pragma unroll
      for (int j = 0; j < 32; ++j) {
        int i = (j + 2 * qq) & 31;           // conflict-free read order
        float v = lsT[(qq * 32 + i) * 68 + r];
        INSERT5(b0, b1, b2, b3, b4, v);
      }
#pragma unroll
      for (int m = 1; m <= 2; m <<= 1) {
        float v0 = __shfl_xor(b0, m);
        float v1 = __shfl_xor(b1, m);
        float v2 = __shfl_xor(b2, m);
        float v3 = __shfl_xor(b3, m);
        float v4 = __shfl_xor(b4, m);
        INSERT5(b0, b1, b2, b3, b4, v0);
        INSERT5(b0, b1, b2, b3, b4, v1);
        INSERT5(b0, b1, b2, b3, b4, v2);
        INSERT5(b0, b1, b2, b3, b4, v3);
        INSERT5(b0, b1, b2, b3, b4, v4);
      }
      if ((tid & 3) == 0) {
        int ng = n0 + (r >> 5) * 64 + p * 32 + (r & 31);
        float sn = sq[ng];
        float* o = part + ((size_t)ng * (NPTS / 128) + bn) * KNN;
        o[0] = b0 + sn;   // squared distances
        o[1] = b1 + sn;
        o[2] = b2 + sn;
        o[3] = b3 + sn;
        o[4] = b4 + sn;
      }
    }
  }
}

// ---------------------------------------------------------------------------
// Kernel 2: fold 64 partial top-5 (of d^2) per query -> per-block (sum, sum2)
// of DISTANCES (sqrt applied to the final 5 only).
__global__ __launch_bounds__(256) void k_merge(const float* __restrict__ part,
                                               double* __restrict__ pacc) {
  __shared__ double red[8];
  int tid = threadIdx.x;
  int q = blockIdx.x * 64 + (tid >> 2);
  int quarter = tid & 3;
  const float4* p =
      (const float4*)(part + ((size_t)q * (NPTS / 128) + quarter * 16) * KNN);
  float b0 = 1e30f, b1 = 1e30f, b2 = 1e30f, b3 = 1e30f, b4 = 1e30f;
#pragma unroll
  for (int i = 0; i < 20; ++i) {
    float4 v = p[i];
    INSERT5(b0, b1, b2, b3, b4, v.x);
    INSERT5(b0, b1, b2, b3, b4, v.y);
    INSERT5(b0, b1, b2, b3, b4, v.z);
    INSERT5(b0, b1, b2, b3, b4, v.w);
  }
#pragma unroll
  for (int m = 1; m <= 2; m <<= 1) {
    float v0 = __shfl_xor(b0, m);
    float v1 = __shfl_xor(b1, m);
    float v2 = __shfl_xor(b2, m);
    float v3 = __shfl_xor(b3, m);
    float v4 = __shfl_xor(b4, m);
    INSERT5(b0, b1, b2, b3, b4, v0);
    INSERT5(b0, b1, b2, b3, b4, v1);
    INSERT5(b0, b1, b2, b3, b4, v2);
    INSERT5(b0, b1, b2, b3, b4, v3);
    INSERT5(b0, b1, b2, b3, b4, v4);
  }
  double ds = 0.0, ds2 = 0.0;
  if ((tid & 3) == 0) {
    float d0 = sqrtf(fmaxf(b0, 0.f));
    float d1 = sqrtf(fmaxf(b1, 0.f));
    float d2 = sqrtf(fmaxf(b2, 0.f));
    float d3 = sqrtf(fmaxf(b3, 0.f));
    float d4 = sqrtf(fmaxf(b4, 0.f));
    float s = d0 + d1 + d2 + d3 + d4;
    float s2 = d0 * d0 + d1 * d1 + d2 * d2 + d3 * d3 + d4 * d4;
    ds = (double)s;
    ds2 = (double)s2;
  }
#pragma unroll
  for (int o = 32; o > 0; o >>= 1) {
    ds += __shfl_down(ds, o);
    ds2 += __shfl_down(ds2, o);
  }
  if ((tid & 63) == 0) {
    red[2 * (tid >> 6)] = ds;
    red[2 * (tid >> 6) + 1] = ds2;
  }
  __syncthreads();
  if (tid == 0) {
    double s = red[0] + red[2] + red[4] + red[6];
    double s2 = red[1] + red[3] + red[5] + red[7];
    pacc[2 * blockIdx.x] = s;
    pacc[2 * blockIdx.x + 1] = s2;
  }
}

// Kernel 3: fold 128 block partials -> -std(knn_dist, ddof=1)
__global__ void k_final(const double* __restrict__ pacc, float* __restrict__ out) {
  int lane = threadIdx.x;
  double s = pacc[2 * lane] + pacc[2 * (lane + 64)];
  double s2 = pacc[2 * lane + 1] + pacc[2 * (lane + 64) + 1];
#pragma unroll
  for (int o = 32; o > 0; o >>= 1) {
    s += __shfl_down(s, o);
    s2 += __shfl_down(s2, o);
  }
  if (lane == 0) {
    double n = (double)NPTS * (double)KNN;
    double mean = s / n;
    double var = (s2 - n * mean * mean) / (n - 1.0);
    if (var < 0.0) var = 0.0;
    out[0] = -(float)sqrt(var);
  }
}

// ---------------------------------------------------------------------------
extern "C" void kernel_launch(void* const* d_in, const int* in_sizes, int n_in,
                              void* d_out, int out_size, void* d_ws, size_t ws_size,
                              hipStream_t stream) {
  const float* X = (const float*)d_in[0];  // latent[0]
  char* ws = (char*)d_ws;

  // ws: part [8192][64][5] f32 (10.5 MB) | sq [8192] f32 | pacc [256] f64 | Xp bf16 packed (8 MB)
  const size_t PART_B = (size_t)NPTS * (NPTS / 128) * KNN * 4;
  float* part = (float*)ws;
  float* sq = (float*)(ws + PART_B);
  double* pacc = (double*)(ws + PART_B + 32768);
  u16* Xp = (u16*)(ws + PART_B + 32768 + 2048);
  float* out = (float*)d_out;

  const int NT = NPTS / 128;                       // 64 tiles per dim
  hipLaunchKernelGGL(k_prep, dim3(NPTS / 4), dim3(256), 0, stream, X, Xp, sq);
  hipLaunchKernelGGL(k_knn_sym, dim3(NT * (NT + 1) / 2), dim3(256), 0, stream,
                     Xp, sq, part);
  hipLaunchKernelGGL(k_merge, dim3(NPTS / 64), dim3(256), 0, stream, part, pacc);
  hipLaunchKernelGGL(k_final, dim3(1), dim3(64), 0, stream, pacc, out);
}

// Round 15
// 75.802 us; speedup vs baseline: 1.0182x; 1.0182x over previous
//
#include <hip/hip_runtime.h>
#include <math.h>

#define NPTS 8192
#define DIM 512
#define KNN 5

typedef unsigned short u16;
typedef unsigned int u32;
typedef __attribute__((ext_vector_type(8))) short short8;
typedef __attribute__((ext_vector_type(4))) float f32x4;
typedef __attribute__((ext_vector_type(16))) float f32x16;

// Branch-free sorted insert of v into ascending 5-list.
// Closed form: t_i' = med3(t_{i-1}, t_i, v) (old values), t0' = min(t0, v).
#define INSERT5(t0, t1, t2, t3, t4, v)                \
  do {                                                \
    float _v = (v);                                   \
    float _n4 = __builtin_amdgcn_fmed3f(t3, t4, _v);  \
    float _n3 = __builtin_amdgcn_fmed3f(t2, t3, _v);  \
    float _n2 = __builtin_amdgcn_fmed3f(t1, t2, _v);  \
    float _n1 = __builtin_amdgcn_fmed3f(t0, t1, _v);  \
    t0 = fminf(t0, _v);                               \
    t1 = _n1; t2 = _n2; t3 = _n3; t4 = _n4;           \
  } while (0)

#define GLDS16(g, l)                                                          \
  __builtin_amdgcn_global_load_lds(                                           \
      (const __attribute__((address_space(1))) u32*)(g),                      \
      (__attribute__((address_space(3))) u32*)(l), 16, 0, 0)

__device__ __forceinline__ u16 f2bf(float f) {
  u32 u = __float_as_uint(f);
  u32 r = (u + 0x7fffu + ((u >> 16) & 1u)) >> 16;  // RNE (no NaN in data)
  return (u16)r;
}

// ---------------------------------------------------------------------------
// Kernel 0: fused bf16 convert (to 64-row-band fragment pack) + row sumsq.
// Band layout: for row r, col k:
//   G = r>>6, mf2 = (r>>5)&1, r32 = r&31; s = k>>5, kk = (k>>4)&1,
//   oct = (k>>3)&1, k8 = k&7
//   addr_u16 = G*32768 + s*2048 + mf2*1024 + kk*512 + (oct*32 + r32)*8 + k8
// One (band G, step s) unit = 2048 u16 = 4KB contiguous -> glds-stageable as
// 4x 1KB pieces. Fragment mapping: lane&31 = row, lane>>5 = k-octet.
__global__ __launch_bounds__(256) void k_prep(const float* __restrict__ X,
                                              u16* __restrict__ Xp,
                                              float* __restrict__ sq) {
  int gt = blockIdx.x * 256 + threadIdx.x;
  int row = gt >> 6;
  int lane = gt & 63;   // this thread holds k = lane*8 .. lane*8+7 (one octet)
  const float* r = X + (size_t)row * DIM + lane * 8;
  float4 a = *(const float4*)r;
  float4 b = *(const float4*)(r + 4);
  float s = a.x * a.x + a.y * a.y + a.z * a.z + a.w * a.w
          + b.x * b.x + b.y * b.y + b.z * b.z + b.w * b.w;
  u32 o0 = (u32)f2bf(a.x) | ((u32)f2bf(a.y) << 16);
  u32 o1 = (u32)f2bf(a.z) | ((u32)f2bf(a.w) << 16);
  u32 o2 = (u32)f2bf(b.x) | ((u32)f2bf(b.y) << 16);
  u32 o3 = (u32)f2bf(b.z) | ((u32)f2bf(b.w) << 16);
  // k = lane*8: s = lane>>2, kk = (lane>>1)&1, oct = lane&1
  u32 dst = (u32)((row >> 6) * 32768 + (lane >> 2) * 2048 +
                  ((row >> 5) & 1) * 1024 + ((lane >> 1) & 1) * 512 +
                  ((lane & 1) * 32 + (row & 31)) * 8);
  *(uint4*)(Xp + dst) = make_uint4(o0, o1, o2, o3);
#pragma unroll
  for (int o = 32; o > 0; o >>= 1) s += __shfl_down(s, o);
  if (lane == 0) sq[row] = s;
}

// ---------------------------------------------------------------------------
// Kernel 1: symmetric bf16 32x32x16-MFMA distance tiles, triangular grid.
// glds+LDS K-loop (R5's proven counted-vmcnt structure, 32x32 frags):
// each (band,step) 4KB unit staged ONCE into a 2x16KB LDS double buffer via
// global_load_lds width-16 -> halves L1 traffic vs flatmm (no 2x re-fetch),
// and frees the frag double-buffer registers -> ~120 unified regs <= 128 ->
// 4 blocks/CU (16 waves). STAGE(next); vmcnt(4); barrier; ds_read_b128 x8;
// lgkmcnt(0); barrier; mfma x8 (setprio). 8x8 super-tile keeps panels in L2.
// C/D: col=lane&31, row=(reg&3)+8*(reg>>2)+4*(lane>>5). part holds SQUARED
// distances (sqrt deferred to k_merge).
__global__ __launch_bounds__(256, 4) void k_knn_sym(
    const u16* __restrict__ Xp, const float* __restrict__ sq,
    float* __restrict__ part) {
  __shared__ __align__(16) char smem[34816];
  u16* ldsu = (u16*)smem;                 // staging dbuf: [2][4 chunks][2048 u16]
  float* mbuf = (float*)smem;             // col-epi merge: [wm*2+wn][nf2][32][5]
  float* lsT = (float*)smem;              // row-epi transpose: [128 cols][68]

  const int tid = threadIdx.x;
  const int lane = tid & 63;
  const int wid = tid >> 6;
  const int wm = wid >> 1;
  const int wn = wid & 1;
  const int lh = lane >> 5;               // k-octet / row-half selector
  const int lane8 = lane * 8;             // u16 offset of this lane's 16B

  // XCD-aware bijective remap (2080 = 8 * 260): each XCD gets 260 consecutive
  // t -> ~one 64-tile 8x8 super-tile at a time (2MB panel set, L2-resident).
  int t = (blockIdx.x & 7) * 260 + (blockIdx.x >> 3);
  int bm, bn;
  if (t < 1792) {
    // off-diagonal super-tiles: st = SM*(SM-1)/2 + SN (SM=1..7, SN<SM)
    int st = t >> 6, u = t & 63;
    int SM = (int)((sqrtf(8.f * st + 1.f) + 1.f) * 0.5f);
    while (SM * (SM - 1) / 2 > st) --SM;
    while ((SM + 1) * SM / 2 <= st) ++SM;
    int SN = st - SM * (SM - 1) / 2;
    bm = SM * 8 + (u >> 3);
    bn = SN * 8 + (u & 7);
  } else {
    // diagonal super-tiles: 8 supers x 36 tiles (triangular 8x8 incl. diag)
    int d = t - 1792;
    int SM = d / 36, u = d % 36;
    int im = (int)((sqrtf(8.f * u + 1.f) - 1.f) * 0.5f);
    while ((im + 1) * (im + 2) / 2 <= u) ++im;
    while (im * (im + 1) / 2 > u) --im;
    int in = u - im * (im + 1) / 2;
    bm = SM * 8 + im;
    bn = SM * 8 + in;
  }
  const int n0 = bm * 128;
  const int q0 = bn * 128;

  // Staging: wave wid owns chunk wid: {A band bm*2+0, A band bm*2+1,
  // B band bn*2+0, B band bn*2+1}. Unit (band, step) = 4KB at
  // Xp_u16[band*32768 + step*2048]; identity-copied to
  // ldsu[buf*8192 + wid*2048].
  const int band_id = (wid < 2) ? (bm * 2 + wid) : (bn * 2 + (wid - 2));
  const u16* srcs = Xp + (size_t)band_id * 32768 + lane8;

#define STAGE(buf, sp)                                   \
  do {                                                   \
    u16* d_ = ldsu + (buf) * 8192 + wid * 2048;          \
    GLDS16((sp), d_);                                    \
    GLDS16((sp) + 512, d_ + 512);                        \
    GLDS16((sp) + 1024, d_ + 1024);                      \
    GLDS16((sp) + 1536, d_ + 1536);                      \
  } while (0)

  f32x16 acc[2][2];
#pragma unroll
  for (int mf2 = 0; mf2 < 2; ++mf2)
#pragma unroll
    for (int nf2 = 0; nf2 < 2; ++nf2)
#pragma unroll
      for (int r = 0; r < 16; ++r) acc[mf2][nf2][r] = 0.f;

  STAGE(0, srcs);                          // stage step 0 -> 4 glds out
  srcs += 2048;

  short8 af[2][2], bf[2][2];
#pragma unroll 1
  for (int step = 0; step < DIM / 32; ++step) {
    const int cur = step & 1;
    if (step < DIM / 32 - 1) {
      STAGE(cur ^ 1, srcs);                // +4 glds -> 8 outstanding
      srcs += 2048;
      asm volatile("s_waitcnt vmcnt(4)" ::: "memory");   // this step's stage done
    } else {
      asm volatile("s_waitcnt vmcnt(0)" ::: "memory");
    }
    __builtin_amdgcn_s_barrier();          // A: stage(step) visible to all waves
    __builtin_amdgcn_sched_barrier(0);
    {
      const u16* ra = ldsu + cur * 8192 + wm * 2048 + lane8;
      const u16* rb = ldsu + cur * 8192 + (2 + wn) * 2048 + lane8;
      af[0][0] = *(const short8*)(ra);
      af[0][1] = *(const short8*)(ra + 512);
      af[1][0] = *(const short8*)(ra + 1024);
      af[1][1] = *(const short8*)(ra + 1536);
      bf[0][0] = *(const short8*)(rb);
      bf[0][1] = *(const short8*)(rb + 512);
      bf[1][0] = *(const short8*)(rb + 1024);
      bf[1][1] = *(const short8*)(rb + 1536);
    }
    asm volatile("s_waitcnt lgkmcnt(0)" ::: "memory");   // reads drained
    __builtin_amdgcn_sched_barrier(0);
    __builtin_amdgcn_s_barrier();          // B: all reads done -> safe overwrite
    __builtin_amdgcn_sched_barrier(0);
    __builtin_amdgcn_s_setprio(1);
#pragma unroll
    for (int kk = 0; kk < 2; ++kk)
#pragma unroll
      for (int mf2 = 0; mf2 < 2; ++mf2)
#pragma unroll
        for (int nf2 = 0; nf2 < 2; ++nf2)
          acc[mf2][nf2] = __builtin_amdgcn_mfma_f32_32x32x16_bf16(
              af[mf2][kk], bf[nf2][kk], acc[mf2][nf2], 0, 0, 0);
    __builtin_amdgcn_s_setprio(0);
  }
#undef STAGE

  // ---- column epilogue: per query-col top-5 of (sq_row - 2*dot) ----
  int qg[2];
  float sqc[2];
#pragma unroll
  for (int nf2 = 0; nf2 < 2; ++nf2) {
    qg[nf2] = q0 + wn * 64 + nf2 * 32 + (lane & 31);
    sqc[nf2] = sq[qg[nf2]];
  }

  float tl[2][5];
#pragma unroll
  for (int nf2 = 0; nf2 < 2; ++nf2)
#pragma unroll
    for (int j = 0; j < 5; ++j) tl[nf2][j] = 1e30f;

  // diagonal mask needed only on the 64 diagonal tiles (uniform branch)
#define COLSCAN(DIAG)                                                         \
  do {                                                                        \
    _Pragma("unroll")                                                         \
    for (int mf2 = 0; mf2 < 2; ++mf2) {                                       \
      _Pragma("unroll")                                                       \
      for (int q2 = 0; q2 < 4; ++q2) {                                        \
        int ngb = n0 + wm * 64 + mf2 * 32 + q2 * 8 + 4 * lh;                  \
        float4 snv = *(const float4*)&sq[ngb];                                \
        _Pragma("unroll")                                                     \
        for (int j = 0; j < 4; ++j) {                                         \
          float sn = (j == 0) ? snv.x : (j == 1) ? snv.y                      \
                   : (j == 2) ? snv.z : snv.w;                                \
          _Pragma("unroll")                                                   \
          for (int nf2 = 0; nf2 < 2; ++nf2) {                                 \
            float c = fmaf(-2.f, acc[mf2][nf2][q2 * 4 + j], sn);              \
            if (DIAG) c = ((ngb + j) == qg[nf2]) ? -1e30f : c;                \
            INSERT5(tl[nf2][0], tl[nf2][1], tl[nf2][2], tl[nf2][3],           \
                    tl[nf2][4], c);                                           \
          }                                                                   \
        }                                                                     \
      }                                                                       \
    }                                                                         \
  } while (0)

  if (bm == bn) COLSCAN(true); else COLSCAN(false);
#undef COLSCAN

  // merge with partner lane^32 (holds the complementary 32 rows, same col)
#pragma unroll
  for (int nf2 = 0; nf2 < 2; ++nf2) {
    float v0 = __shfl_xor(tl[nf2][0], 32);
    float v1 = __shfl_xor(tl[nf2][1], 32);
    float v2 = __shfl_xor(tl[nf2][2], 32);
    float v3 = __shfl_xor(tl[nf2][3], 32);
    float v4 = __shfl_xor(tl[nf2][4], 32);
    INSERT5(tl[nf2][0], tl[nf2][1], tl[nf2][2], tl[nf2][3], tl[nf2][4], v0);
    INSERT5(tl[nf2][0], tl[nf2][1], tl[nf2][2], tl[nf2][3], tl[nf2][4], v1);
    INSERT5(tl[nf2][0], tl[nf2][1], tl[nf2][2], tl[nf2][3], tl[nf2][4], v2);
    INSERT5(tl[nf2][0], tl[nf2][1], tl[nf2][2], tl[nf2][3], tl[nf2][4], v3);
    INSERT5(tl[nf2][0], tl[nf2][1], tl[nf2][2], tl[nf2][3], tl[nf2][4], v4);
  }

  __syncthreads();                         // staging done; reuse smem as mbuf
  if (lane < 32) {
#pragma unroll
    for (int nf2 = 0; nf2 < 2; ++nf2)
#pragma unroll
      for (int j = 0; j < 5; ++j)
        mbuf[(((wm * 2 + wn) * 2 + nf2) * 32 + lane) * 5 + j] = tl[nf2][j];
  }
  __syncthreads();

  if (tid < 128) {
    int wn2 = tid >> 6, nf2 = (tid >> 5) & 1, q = tid & 31;
    const float* m0 = &mbuf[(((0 * 2 + wn2) * 2 + nf2) * 32 + q) * 5];
    const float* m1 = &mbuf[(((1 * 2 + wn2) * 2 + nf2) * 32 + q) * 5];
    float b0 = m0[0], b1 = m0[1], b2 = m0[2], b3 = m0[3], b4 = m0[4];
#pragma unroll
    for (int j = 0; j < 5; ++j) {
      float v = m1[j];
      INSERT5(b0, b1, b2, b3, b4, v);
    }
    int qgl = q0 + wn2 * 64 + nf2 * 32 + q;
    float sc = sq[qgl];
    float* o = part + ((size_t)qgl * (NPTS / 128) + bm) * KNN;
    o[0] = b0 + sc;   // squared distances; sqrt deferred to k_merge
    o[1] = b1 + sc;
    o[2] = b2 + sc;
    o[3] = b3 + sc;
    o[4] = b4 + sc;
  }

  // ---- row epilogue (off-diagonal blocks): queries = this tile's rows ----
  // pass p = mf2: rows {wm*64 + p*32 + w32} through lsT[128 cols][68 rows].
  if (bm != bn) {
#pragma unroll
    for (int p = 0; p < 2; ++p) {
      __syncthreads();                     // protect mbuf / previous lsT readers
#pragma unroll
      for (int nf2 = 0; nf2 < 2; ++nf2) {
        int cl = wn * 64 + nf2 * 32 + (lane & 31);
#pragma unroll
        for (int q2 = 0; q2 < 4; ++q2) {
          int rl = wm * 32 + q2 * 8 + 4 * lh;
          f32x4 cp;
#pragma unroll
          for (int j = 0; j < 4; ++j)
            cp[j] = fmaf(-2.f, acc[p][nf2][q2 * 4 + j], sqc[nf2]);
          *(f32x4*)&lsT[cl * 68 + rl] = cp;   // 16B-aligned (rl%4==0)
        }
      }
      __syncthreads();
      int r = tid >> 2, qq = tid & 3;        // 4 threads per row, 32 cols each
      float b0 = 1e30f, b1 = 1e30f, b2 = 1e30f, b3 = 1e30f, b4 = 1e30f;
#pragma unroll
      for (int j = 0; j < 32; ++j) {
        int i = (j + 2 * qq) & 31;           // conflict-free read order
        float v = lsT[(qq * 32 + i) * 68 + r];
        INSERT5(b0, b1, b2, b3, b4, v);
      }
#pragma unroll
      for (int m = 1; m <= 2; m <<= 1) {
        float v0 = __shfl_xor(b0, m);
        float v1 = __shfl_xor(b1, m);
        float v2 = __shfl_xor(b2, m);
        float v3 = __shfl_xor(b3, m);
        float v4 = __shfl_xor(b4, m);
        INSERT5(b0, b1, b2, b3, b4, v0);
        INSERT5(b0, b1, b2, b3, b4, v1);
        INSERT5(b0, b1, b2, b3, b4, v2);
        INSERT5(b0, b1, b2, b3, b4, v3);
        INSERT5(b0, b1, b2, b3, b4, v4);
      }
      if ((tid & 3) == 0) {
        int ng = n0 + (r >> 5) * 64 + p * 32 + (r & 31);
        float sn = sq[ng];
        float* o = part + ((size_t)ng * (NPTS / 128) + bn) * KNN;
        o[0] = b0 + sn;   // squared distances
        o[1] = b1 + sn;
        o[2] = b2 + sn;
        o[3] = b3 + sn;
        o[4] = b4 + sn;
      }
    }
  }
}

// ---------------------------------------------------------------------------
// Kernel 2: fold 64 partial top-5 (of d^2) per query -> per-block (sum, sum2)
// of DISTANCES (sqrt applied to the final 5 only).
__global__ __launch_bounds__(256) void k_merge(const float* __restrict__ part,
                                               double* __restrict__ pacc) {
  __shared__ double red[8];
  int tid = threadIdx.x;
  int q = blockIdx.x * 64 + (tid >> 2);
  int quarter = tid & 3;
  const float4* p =
      (const float4*)(part + ((size_t)q * (NPTS / 128) + quarter * 16) * KNN);
  float b0 = 1e30f, b1 = 1e30f, b2 = 1e30f, b3 = 1e30f, b4 = 1e30f;
#pragma unroll
  for (int i = 0; i < 20; ++i) {
    float4 v = p[i];
    INSERT5(b0, b1, b2, b3, b4, v.x);
    INSERT5(b0, b1, b2, b3, b4, v.y);
    INSERT5(b0, b1, b2, b3, b4, v.z);
    INSERT5(b0, b1, b2, b3, b4, v.w);
  }
#pragma unroll
  for (int m = 1; m <= 2; m <<= 1) {
    float v0 = __shfl_xor(b0, m);
    float v1 = __shfl_xor(b1, m);
    float v2 = __shfl_xor(b2, m);
    float v3 = __shfl_xor(b3, m);
    float v4 = __shfl_xor(b4, m);
    INSERT5(b0, b1, b2, b3, b4, v0);
    INSERT5(b0, b1, b2, b3, b4, v1);
    INSERT5(b0, b1, b2, b3, b4, v2);
    INSERT5(b0, b1, b2, b3, b4, v3);
    INSERT5(b0, b1, b2, b3, b4, v4);
  }
  double ds = 0.0, ds2 = 0.0;
  if ((tid & 3) == 0) {
    float d0 = sqrtf(fmaxf(b0, 0.f));
    float d1 = sqrtf(fmaxf(b1, 0.f));
    float d2 = sqrtf(fmaxf(b2, 0.f));
    float d3 = sqrtf(fmaxf(b3, 0.f));
    float d4 = sqrtf(fmaxf(b4, 0.f));
    float s = d0 + d1 + d2 + d3 + d4;
    float s2 = d0 * d0 + d1 * d1 + d2 * d2 + d3 * d3 + d4 * d4;
    ds = (double)s;
    ds2 = (double)s2;
  }
#pragma unroll
  for (int o = 32; o > 0; o >>= 1) {
    ds += __shfl_down(ds, o);
    ds2 += __shfl_down(ds2, o);
  }
  if ((tid & 63) == 0) {
    red[2 * (tid >> 6)] = ds;
    red[2 * (tid >> 6) + 1] = ds2;
  }
  __syncthreads();
  if (tid == 0) {
    double s = red[0] + red[2] + red[4] + red[6];
    double s2 = red[1] + red[3] + red[5] + red[7];
    pacc[2 * blockIdx.x] = s;
    pacc[2 * blockIdx.x + 1] = s2;
  }
}

// Kernel 3: fold 128 block partials -> -std(knn_dist, ddof=1)
__global__ void k_final(const double* __restrict__ pacc, float* __restrict__ out) {
  int lane = threadIdx.x;
  double s = pacc[2 * lane] + pacc[2 * (lane + 64)];
  double s2 = pacc[2 * lane + 1] + pacc[2 * (lane + 64) + 1];
#pragma unroll
  for (int o = 32; o > 0; o >>= 1) {
    s += __shfl_down(s, o);
    s2 += __shfl_down(s2, o);
  }
  if (lane == 0) {
    double n = (double)NPTS * (double)KNN;
    double mean = s / n;
    double var = (s2 - n * mean * mean) / (n - 1.0);
    if (var < 0.0) var = 0.0;
    out[0] = -(float)sqrt(var);
  }
}

// ---------------------------------------------------------------------------
extern "C" void kernel_launch(void* const* d_in, const int* in_sizes, int n_in,
                              void* d_out, int out_size, void* d_ws, size_t ws_size,
                              hipStream_t stream) {
  const float* X = (const float*)d_in[0];  // latent[0]
  char* ws = (char*)d_ws;

  // ws: part [8192][64][5] f32 (10.5 MB) | sq [8192] f32 | pacc [256] f64 | Xp bf16 packed (8 MB)
  const size_t PART_B = (size_t)NPTS * (NPTS / 128) * KNN * 4;
  float* part = (float*)ws;
  float* sq = (float*)(ws + PART_B);
  double* pacc = (double*)(ws + PART_B + 32768);
  u16* Xp = (u16*)(ws + PART_B + 32768 + 2048);
  float* out = (float*)d_out;

  const int NT = NPTS / 128;                       // 64 tiles per dim
  hipLaunchKernelGGL(k_prep, dim3(NPTS / 4), dim3(256), 0, stream, X, Xp, sq);
  hipLaunchKernelGGL(k_knn_sym, dim3(NT * (NT + 1) / 2), dim3(256), 0, stream,
                     Xp, sq, part);
  hipLaunchKernelGGL(k_merge, dim3(NPTS / 64), dim3(256), 0, stream, part, pacc);
  hipLaunchKernelGGL(k_final, dim3(1), dim3(64), 0, stream, pacc, out);
}

// Round 16
// 60.958 us; speedup vs baseline: 1.2661x; 1.2435x over previous
//
#include <hip/hip_runtime.h>
#include <math.h>

#define NPTS 8192
#define DIM 512
#define KNN 5

typedef unsigned short u16;
typedef unsigned char u8;
typedef unsigned int u32;
typedef __attribute__((ext_vector_type(2))) long longx2;
typedef __attribute__((ext_vector_type(4))) float f32x4;
typedef __attribute__((ext_vector_type(16))) float f32x16;

// Branch-free sorted insert of v into ascending 5-list.
// Closed form: t_i' = med3(t_{i-1}, t_i, v) (old values), t0' = min(t0, v).
#define INSERT5(t0, t1, t2, t3, t4, v)                \
  do {                                                \
    float _v = (v);                                   \
    float _n4 = __builtin_amdgcn_fmed3f(t3, t4, _v);  \
    float _n3 = __builtin_amdgcn_fmed3f(t2, t3, _v);  \
    float _n2 = __builtin_amdgcn_fmed3f(t1, t2, _v);  \
    float _n1 = __builtin_amdgcn_fmed3f(t0, t1, _v);  \
    t0 = fminf(t0, _v);                               \
    t1 = _n1; t2 = _n2; t3 = _n3; t4 = _n4;           \
  } while (0)

// ---------------------------------------------------------------------------
// Kernel 0: fused fp8-e4m3 convert (to 32x32x16-fp8-MFMA band pack) + sumsq.
// fp8 A/B fragment (2 VGPR, 8 bytes): row = lane&31, k = (lane>>5)*8 + byte
// within a K-16 block (same index structure as bf16 32x32x16, 1B elements).
// Band layout (64 rows, byte address within Xp8):
//   band G = row>>6 (32768 B); iter I = k>>6 (4096 B);
//   mf2 = (row>>5)&1 (2048); c = (k>>5)&1 (1024);
//   frag_lane = ((k>>3)&1)*32 + (row&31) (16 B); h = (k>>4)&1 (8);
//   byte b = k&7.
// => k_knn loads ONE dwordx4 (16 B) per (mf2,c): [h=0 frag | h=1 frag].
__global__ __launch_bounds__(256) void k_prep(const float* __restrict__ X,
                                              u8* __restrict__ Xp8,
                                              float* __restrict__ sq) {
  int gt = blockIdx.x * 256 + threadIdx.x;
  int row = gt >> 6;
  int lane = gt & 63;   // holds k = lane*8 .. lane*8+7 (one 8-byte octet)
  const float* r = X + (size_t)row * DIM + lane * 8;
  float4 a = *(const float4*)r;
  float4 b = *(const float4*)(r + 4);
  float s = a.x * a.x + a.y * a.y + a.z * a.z + a.w * a.w
          + b.x * b.x + b.y * b.y + b.z * b.z + b.w * b.w;
  u32 w0 = __builtin_amdgcn_cvt_pk_fp8_f32(a.x, a.y, 0u, false);
  w0 = __builtin_amdgcn_cvt_pk_fp8_f32(a.z, a.w, w0, true);
  u32 w1 = __builtin_amdgcn_cvt_pk_fp8_f32(b.x, b.y, 0u, false);
  w1 = __builtin_amdgcn_cvt_pk_fp8_f32(b.z, b.w, w1, true);
  // k0 = lane*8: I = lane>>3, c = (lane>>2)&1, h = (lane>>1)&1, half = lane&1
  u32 dst = (u32)((row >> 6) * 32768 + (lane >> 3) * 4096 +
                  ((row >> 5) & 1) * 2048 + ((lane >> 2) & 1) * 1024 +
                  ((lane & 1) * 32 + (row & 31)) * 16 + ((lane >> 1) & 1) * 8);
  *(uint2*)(Xp8 + dst) = make_uint2(w0, w1);
#pragma unroll
  for (int o = 32; o > 0; o >>= 1) s += __shfl_down(s, o);
  if (lane == 0) sq[row] = s;
}

// ---------------------------------------------------------------------------
// Kernel 1: symmetric fp8 32x32x16-MFMA distance tiles, triangular grid.
// Flatmm K-loop (global->VGPR, double-buffered, R12 schedule) but fp8:
// one 16B load = TWO K-16 fragments -> per iter K=64 with the same 128 B/lane
// as the bf16 K=32 iter => L1 traffic HALVED, 8 iters. MFMA floor unchanged
// (fp8 non-scaled = bf16 rate). 8x8 super-tile keeps panels L2-resident.
// C/D layout dtype-independent: col=lane&31, row=(reg&3)+8*(reg>>2)+4*(lane>>5)
// -> epilogues identical to R12. part holds SQUARED distances.
__global__ __launch_bounds__(256, 3) void k_knn_sym(
    const u8* __restrict__ Xp8, const float* __restrict__ sq,
    float* __restrict__ part) {
  __shared__ __align__(16) char smem[34816];
  float* mbuf = (float*)smem;             // col-epi merge: [wm*2+wn][nf2][32][5]
  float* lsT = (float*)smem;              // row-epi transpose: [128 cols][68]

  const int tid = threadIdx.x;
  const int lane = tid & 63;
  const int wid = tid >> 6;
  const int wm = wid >> 1;
  const int wn = wid & 1;
  const int lh = lane >> 5;               // row-half selector for C/D

  // XCD-aware bijective remap (2080 = 8 * 260): each XCD gets 260 consecutive
  // t -> ~one 64-tile 8x8 super-tile at a time (1MB fp8 panel set in L2).
  int t = (blockIdx.x & 7) * 260 + (blockIdx.x >> 3);
  int bm, bn;
  if (t < 1792) {
    // off-diagonal super-tiles: st = SM*(SM-1)/2 + SN (SM=1..7, SN<SM)
    int st = t >> 6, u = t & 63;
    int SM = (int)((sqrtf(8.f * st + 1.f) + 1.f) * 0.5f);
    while (SM * (SM - 1) / 2 > st) --SM;
    while ((SM + 1) * SM / 2 <= st) ++SM;
    int SN = st - SM * (SM - 1) / 2;
    bm = SM * 8 + (u >> 3);
    bn = SN * 8 + (u & 7);
  } else {
    // diagonal super-tiles: 8 supers x 36 tiles (triangular 8x8 incl. diag)
    int d = t - 1792;
    int SM = d / 36, u = d % 36;
    int im = (int)((sqrtf(8.f * u + 1.f) - 1.f) * 0.5f);
    while ((im + 1) * (im + 2) / 2 <= u) ++im;
    while (im * (im + 1) / 2 > u) --im;
    int in = u - im * (im + 1) / 2;
    bm = SM * 8 + im;
    bn = SM * 8 + in;
  }
  const int n0 = bm * 128;
  const int q0 = bn * 128;

  // Band pointers: band (64 rows) = 32768 B; advance 4096 B per K-64 iter.
  const u8* pa = Xp8 + (size_t)(bm * 2 + wm) * 32768 + lane * 16;
  const u8* pb = Xp8 + (size_t)(bn * 2 + wn) * 32768 + lane * 16;

  // [buf][mf2][c]: 16B = {h=0 frag (kk=2c), h=1 frag (kk=2c+1)}
  longx2 afr[2][2][2], bfr[2][2][2];
#define LOADF(buf)                                     \
  do {                                                 \
    afr[buf][0][0] = *(const longx2*)(pa);             \
    afr[buf][0][1] = *(const longx2*)(pa + 1024);      \
    afr[buf][1][0] = *(const longx2*)(pa + 2048);      \
    afr[buf][1][1] = *(const longx2*)(pa + 3072);      \
    bfr[buf][0][0] = *(const longx2*)(pb);             \
    bfr[buf][0][1] = *(const longx2*)(pb + 1024);      \
    bfr[buf][1][0] = *(const longx2*)(pb + 2048);      \
    bfr[buf][1][1] = *(const longx2*)(pb + 3072);      \
  } while (0)

  f32x16 acc[2][2];
#pragma unroll
  for (int mf2 = 0; mf2 < 2; ++mf2)
#pragma unroll
    for (int nf2 = 0; nf2 < 2; ++nf2)
#pragma unroll
      for (int r = 0; r < 16; ++r) acc[mf2][nf2][r] = 0.f;

  LOADF(0);

#pragma unroll
  for (int step = 0; step < DIM / 64; ++step) {        // 8 iters of K=64
    const int cur = step & 1;
    if (step < DIM / 64 - 1) {
      pa += 4096;
      pb += 4096;
      LOADF(cur ^ 1);                                  // prefetch next iter
    }
    __builtin_amdgcn_sched_barrier(0);
    __builtin_amdgcn_s_setprio(1);
#pragma unroll
    for (int c = 0; c < 2; ++c)
#pragma unroll
      for (int h = 0; h < 2; ++h)
#pragma unroll
        for (int mf2 = 0; mf2 < 2; ++mf2)
#pragma unroll
          for (int nf2 = 0; nf2 < 2; ++nf2)
            acc[mf2][nf2] = __builtin_amdgcn_mfma_f32_32x32x16_fp8_fp8(
                (h == 0) ? afr[cur][mf2][c].x : afr[cur][mf2][c].y,
                (h == 0) ? bfr[cur][nf2][c].x : bfr[cur][nf2][c].y,
                acc[mf2][nf2], 0, 0, 0);
    __builtin_amdgcn_s_setprio(0);
  }
#undef LOADF

  // ---- column epilogue: per query-col top-5 of (sq_row - 2*dot) ----
  int qg[2];
  float sqc[2];
#pragma unroll
  for (int nf2 = 0; nf2 < 2; ++nf2) {
    qg[nf2] = q0 + wn * 64 + nf2 * 32 + (lane & 31);
    sqc[nf2] = sq[qg[nf2]];
  }

  float tl[2][5];
#pragma unroll
  for (int nf2 = 0; nf2 < 2; ++nf2)
#pragma unroll
    for (int j = 0; j < 5; ++j) tl[nf2][j] = 1e30f;

  // diagonal mask needed only on the 64 diagonal tiles (uniform branch)
#define COLSCAN(DIAG)                                                         \
  do {                                                                        \
    _Pragma("unroll")                                                         \
    for (int mf2 = 0; mf2 < 2; ++mf2) {                                       \
      _Pragma("unroll")                                                       \
      for (int q2 = 0; q2 < 4; ++q2) {                                        \
        int ngb = n0 + wm * 64 + mf2 * 32 + q2 * 8 + 4 * lh;                  \
        float4 snv = *(const float4*)&sq[ngb];                                \
        _Pragma("unroll")                                                     \
        for (int j = 0; j < 4; ++j) {                                         \
          float sn = (j == 0) ? snv.x : (j == 1) ? snv.y                      \
                   : (j == 2) ? snv.z : snv.w;                                \
          _Pragma("unroll")                                                   \
          for (int nf2 = 0; nf2 < 2; ++nf2) {                                 \
            float c = fmaf(-2.f, acc[mf2][nf2][q2 * 4 + j], sn);              \
            if (DIAG) c = ((ngb + j) == qg[nf2]) ? -1e30f : c;                \
            INSERT5(tl[nf2][0], tl[nf2][1], tl[nf2][2], tl[nf2][3],           \
                    tl[nf2][4], c);                                           \
          }                                                                   \
        }                                                                     \
      }                                                                       \
    }                                                                         \
  } while (0)

  if (bm == bn) COLSCAN(true); else COLSCAN(false);
#undef COLSCAN

  // merge with partner lane^32 (holds the complementary 32 rows, same col)
#pragma unroll
  for (int nf2 = 0; nf2 < 2; ++nf2) {
    float v0 = __shfl_xor(tl[nf2][0], 32);
    float v1 = __shfl_xor(tl[nf2][1], 32);
    float v2 = __shfl_xor(tl[nf2][2], 32);
    float v3 = __shfl_xor(tl[nf2][3], 32);
    float v4 = __shfl_xor(tl[nf2][4], 32);
    INSERT5(tl[nf2][0], tl[nf2][1], tl[nf2][2], tl[nf2][3], tl[nf2][4], v0);
    INSERT5(tl[nf2][0], tl[nf2][1], tl[nf2][2], tl[nf2][3], tl[nf2][4], v1);
    INSERT5(tl[nf2][0], tl[nf2][1], tl[nf2][2], tl[nf2][3], tl[nf2][4], v2);
    INSERT5(tl[nf2][0], tl[nf2][1], tl[nf2][2], tl[nf2][3], tl[nf2][4], v3);
    INSERT5(tl[nf2][0], tl[nf2][1], tl[nf2][2], tl[nf2][3], tl[nf2][4], v4);
  }

  if (lane < 32) {
#pragma unroll
    for (int nf2 = 0; nf2 < 2; ++nf2)
#pragma unroll
      for (int j = 0; j < 5; ++j)
        mbuf[(((wm * 2 + wn) * 2 + nf2) * 32 + lane) * 5 + j] = tl[nf2][j];
  }
  __syncthreads();

  if (tid < 128) {
    int wn2 = tid >> 6, nf2 = (tid >> 5) & 1, q = tid & 31;
    const float* m0 = &mbuf[(((0 * 2 + wn2) * 2 + nf2) * 32 + q) * 5];
    const float* m1 = &mbuf[(((1 * 2 + wn2) * 2 + nf2) * 32 + q) * 5];
    float b0 = m0[0], b1 = m0[1], b2 = m0[2], b3 = m0[3], b4 = m0[4];
#pragma unroll
    for (int j = 0; j < 5; ++j) {
      float v = m1[j];
      INSERT5(b0, b1, b2, b3, b4, v);
    }
    int qgl = q0 + wn2 * 64 + nf2 * 32 + q;
    float sc = sq[qgl];
    float* o = part + ((size_t)qgl * (NPTS / 128) + bm) * KNN;
    o[0] = b0 + sc;   // squared distances; sqrt deferred to k_merge
    o[1] = b1 + sc;
    o[2] = b2 + sc;
    o[3] = b3 + sc;
    o[4] = b4 + sc;
  }

  // ---- row epilogue (off-diagonal blocks): queries = this tile's rows ----
  // pass p = mf2: rows {wm*64 + p*32 + w32} through lsT[128 cols][68 rows].
  if (bm != bn) {
#pragma unroll
    for (int p = 0; p < 2; ++p) {
      __syncthreads();                     // protect mbuf / previous lsT readers
#pragma unroll
      for (int nf2 = 0; nf2 < 2; ++nf2) {
        int cl = wn * 64 + nf2 * 32 + (lane & 31);
#pragma unroll
        for (int q2 = 0; q2 < 4; ++q2) {
          int rl = wm * 32 + q2 * 8 + 4 * lh;
          f32x4 cp;
#pragma unroll
          for (int j = 0; j < 4; ++j)
            cp[j] = fmaf(-2.f, acc[p][nf2][q2 * 4 + j], sqc[nf2]);
          *(f32x4*)&lsT[cl * 68 + rl] = cp;   // 16B-aligned (rl%4==0)
        }
      }
      __syncthreads();
      int r = tid >> 2, qq = tid & 3;        // 4 threads per row, 32 cols each
      float b0 = 1e30f, b1 = 1e30f, b2 = 1e30f, b3 = 1e30f, b4 = 1e30f;
#pragma unroll
      for (int j = 0; j < 32; ++j) {
        int i = (j + 2 * qq) & 31;           // conflict-free read order
        float v = lsT[(qq * 32 + i) * 68 + r];
        INSERT5(b0, b1, b2, b3, b4, v);
      }
#pragma unroll
      for (int m = 1; m <= 2; m <<= 1) {
        float v0 = __shfl_xor(b0, m);
        float v1 = __shfl_xor(b1, m);
        float v2 = __shfl_xor(b2, m);
        float v3 = __shfl_xor(b3, m);
        float v4 = __shfl_xor(b4, m);
        INSERT5(b0, b1, b2, b3, b4, v0);
        INSERT5(b0, b1, b2, b3, b4, v1);
        INSERT5(b0, b1, b2, b3, b4, v2);
        INSERT5(b0, b1, b2, b3, b4, v3);
        INSERT5(b0, b1, b2, b3, b4, v4);
      }
      if ((tid & 3) == 0) {
        int ng = n0 + (r >> 5) * 64 + p * 32 + (r & 31);
        float sn = sq[ng];
        float* o = part + ((size_t)ng * (NPTS / 128) + bn) * KNN;
        o[0] = b0 + sn;   // squared distances
        o[1] = b1 + sn;
        o[2] = b2 + sn;
        o[3] = b3 + sn;
        o[4] = b4 + sn;
      }
    }
  }
}

// ---------------------------------------------------------------------------
// Kernel 2: fold 64 partial top-5 (of d^2) per query -> per-block (sum, sum2)
// of DISTANCES (sqrt applied to the final 5 only).
__global__ __launch_bounds__(256) void k_merge(const float* __restrict__ part,
                                               double* __restrict__ pacc) {
  __shared__ double red[8];
  int tid = threadIdx.x;
  int q = blockIdx.x * 64 + (tid >> 2);
  int quarter = tid & 3;
  const float4* p =
      (const float4*)(part + ((size_t)q * (NPTS / 128) + quarter * 16) * KNN);
  float b0 = 1e30f, b1 = 1e30f, b2 = 1e30f, b3 = 1e30f, b4 = 1e30f;
#pragma unroll
  for (int i = 0; i < 20; ++i) {
    float4 v = p[i];
    INSERT5(b0, b1, b2, b3, b4, v.x);
    INSERT5(b0, b1, b2, b3, b4, v.y);
    INSERT5(b0, b1, b2, b3, b4, v.z);
    INSERT5(b0, b1, b2, b3, b4, v.w);
  }
#pragma unroll
  for (int m = 1; m <= 2; m <<= 1) {
    float v0 = __shfl_xor(b0, m);
    float v1 = __shfl_xor(b1, m);
    float v2 = __shfl_xor(b2, m);
    float v3 = __shfl_xor(b3, m);
    float v4 = __shfl_xor(b4, m);
    INSERT5(b0, b1, b2, b3, b4, v0);
    INSERT5(b0, b1, b2, b3, b4, v1);
    INSERT5(b0, b1, b2, b3, b4, v2);
    INSERT5(b0, b1, b2, b3, b4, v3);
    INSERT5(b0, b1, b2, b3, b4, v4);
  }
  double ds = 0.0, ds2 = 0.0;
  if ((tid & 3) == 0) {
    float d0 = sqrtf(fmaxf(b0, 0.f));
    float d1 = sqrtf(fmaxf(b1, 0.f));
    float d2 = sqrtf(fmaxf(b2, 0.f));
    float d3 = sqrtf(fmaxf(b3, 0.f));
    float d4 = sqrtf(fmaxf(b4, 0.f));
    float s = d0 + d1 + d2 + d3 + d4;
    float s2 = d0 * d0 + d1 * d1 + d2 * d2 + d3 * d3 + d4 * d4;
    ds = (double)s;
    ds2 = (double)s2;
  }
#pragma unroll
  for (int o = 32; o > 0; o >>= 1) {
    ds += __shfl_down(ds, o);
    ds2 += __shfl_down(ds2, o);
  }
  if ((tid & 63) == 0) {
    red[2 * (tid >> 6)] = ds;
    red[2 * (tid >> 6) + 1] = ds2;
  }
  __syncthreads();
  if (tid == 0) {
    double s = red[0] + red[2] + red[4] + red[6];
    double s2 = red[1] + red[3] + red[5] + red[7];
    pacc[2 * blockIdx.x] = s;
    pacc[2 * blockIdx.x + 1] = s2;
  }
}

// Kernel 3: fold 128 block partials -> -std(knn_dist, ddof=1)
__global__ void k_final(const double* __restrict__ pacc, float* __restrict__ out) {
  int lane = threadIdx.x;
  double s = pacc[2 * lane] + pacc[2 * (lane + 64)];
  double s2 = pacc[2 * lane + 1] + pacc[2 * (lane + 64) + 1];
#pragma unroll
  for (int o = 32; o > 0; o >>= 1) {
    s += __shfl_down(s, o);
    s2 += __shfl_down(s2, o);
  }
  if (lane == 0) {
    double n = (double)NPTS * (double)KNN;
    double mean = s / n;
    double var = (s2 - n * mean * mean) / (n - 1.0);
    if (var < 0.0) var = 0.0;
    out[0] = -(float)sqrt(var);
  }
}

// ---------------------------------------------------------------------------
extern "C" void kernel_launch(void* const* d_in, const int* in_sizes, int n_in,
                              void* d_out, int out_size, void* d_ws, size_t ws_size,
                              hipStream_t stream) {
  const float* X = (const float*)d_in[0];  // latent[0]
  char* ws = (char*)d_ws;

  // ws: part [8192][64][5] f32 (10.5 MB) | sq [8192] f32 | pacc [256] f64 | Xp8 fp8 packed (4 MB)
  const size_t PART_B = (size_t)NPTS * (NPTS / 128) * KNN * 4;
  float* part = (float*)ws;
  float* sq = (float*)(ws + PART_B);
  double* pacc = (double*)(ws + PART_B + 32768);
  u8* Xp8 = (u8*)(ws + PART_B + 32768 + 2048);
  float* out = (float*)d_out;

  const int NT = NPTS / 128;                       // 64 tiles per dim
  hipLaunchKernelGGL(k_prep, dim3(NPTS / 4), dim3(256), 0, stream, X, Xp8, sq);
  hipLaunchKernelGGL(k_knn_sym, dim3(NT * (NT + 1) / 2), dim3(256), 0, stream,
                     Xp8, sq, part);
  hipLaunchKernelGGL(k_merge, dim3(NPTS / 64), dim3(256), 0, stream, part, pacc);
  hipLaunchKernelGGL(k_final, dim3(1), dim3(64), 0, stream, pacc, out);
}